// Round 2
// baseline (38562.274 us; speedup 1.0000x reference)
//
#include <hip/hip_runtime.h>
#include <stddef.h>

// Elman RNN: out[t,b,u] = h_t = tanh(x_t @ Wx + h_{t-1} @ Wh + bias)
// B=128, T=512, D=128, U=512. Output [T, B, U] float32.
//
// Kernel 1 (pgemm): P[t*B+b, u] = x[b,t,:]@Wx[:,u] + bias[u] -> written to d_out.
// Kernel 2 (rnn):   one WG (1024 thr) per batch row; Wh register-stationary as
//   16 NAMED f32x16 SSA values per thread (no alloca -> no scratch demotion),
//   __launch_bounds__(1024,4) -> VGPR budget 512. Per step: 256 reg FMAs/thread,
//   LDS partial reduce, tanh, in-place overwrite of P row with h row.

constexpr int B = 128;
constexpr int T = 512;
constexpr int D = 128;
constexpr int U = 512;

typedef float f32x16 __attribute__((ext_vector_type(16)));

// ---------------------------------------------------------------------------
// Kernel 1: P = x @ Wx + bias   (M=T*B rows in (t,b) order, K=D, N=U)
// ---------------------------------------------------------------------------
__global__ __launch_bounds__(256) void pgemm_kernel(
    const float* __restrict__ x,     // [B, T, D]
    const float* __restrict__ Wx,    // [D, U]
    const float* __restrict__ bias,  // [U]
    float* __restrict__ P)           // [T*B, U]  (== d_out)
{
    __shared__ float xs[128][65];    // [row][k] padded
    __shared__ float ws[64][128];    // [k][col]

    const int rb  = blockIdx.x;      // 512 row blocks of 128
    const int cb  = blockIdx.y;      // 4 col blocks of 128
    const int tid = threadIdx.x;
    const int tr  = tid >> 4;        // 0..15
    const int tcc = tid & 15;        // 0..15

    float acc[8][8];
#pragma unroll
    for (int i = 0; i < 8; ++i)
#pragma unroll
        for (int j = 0; j < 8; ++j) acc[i][j] = 0.f;

    for (int kb = 0; kb < 2; ++kb) {
#pragma unroll
        for (int l = 0; l < 32; ++l) {
            int idx = tid + l * 256;
            int r   = idx >> 6;
            int k   = idx & 63;
            int m   = rb * 128 + r;
            int b_  = m & 127;
            int t_  = m >> 7;
            xs[r][k] = x[((size_t)b_ * T + t_) * D + kb * 64 + k];
        }
#pragma unroll
        for (int l = 0; l < 32; ++l) {
            int idx = tid + l * 256;
            int k   = idx >> 7;
            int c   = idx & 127;
            ws[k][c] = Wx[(size_t)(kb * 64 + k) * U + cb * 128 + c];
        }
        __syncthreads();

#pragma unroll 4
        for (int k = 0; k < 64; ++k) {
            float xv[8], wv[8];
#pragma unroll
            for (int i = 0; i < 8; ++i) xv[i] = xs[tr + 16 * i][k];
#pragma unroll
            for (int j = 0; j < 8; ++j) wv[j] = ws[k][tcc + 16 * j];
#pragma unroll
            for (int i = 0; i < 8; ++i)
#pragma unroll
                for (int j = 0; j < 8; ++j)
                    acc[i][j] += xv[i] * wv[j];
        }
        __syncthreads();
    }

#pragma unroll
    for (int j = 0; j < 8; ++j) {
        int c    = cb * 128 + tcc + 16 * j;
        float bv = bias[c];
#pragma unroll
        for (int i = 0; i < 8; ++i) {
            int m = rb * 128 + tr + 16 * i;
            P[(size_t)m * U + c] = acc[i][j] + bv;
        }
    }
}

// ---------------------------------------------------------------------------
// Kernel 2: recurrence. One WG (1024 threads) per batch row b.
//   tk = tid>>5 (0..31): owns k in [tk*16, tk*16+16)
//   tc = tid&31 (0..31): owns cols {tc + 32*j, j<16}
//   Wh block: 16 named f32x16 values (rows i = tk*16+i, col lane j -> tc+32*j).
// ---------------------------------------------------------------------------
__global__ __launch_bounds__(1024, 4) void rnn_kernel(
    const float* __restrict__ Wh,    // [U, U]
    float* __restrict__ out)         // [T*B, U]; P on entry, h on exit
{
    __shared__ float h_lds[U];       // 2 KB
    __shared__ float part[U][33];    // 67.6 KB, +1 pad -> (tc+tk)%32 banks
    const int b   = blockIdx.x;
    const int tid = threadIdx.x;
    const int tk  = tid >> 5;        // 0..31
    const int tc  = tid & 31;        // 0..31

    // Register-stationary Wh: 16 named SSA vectors, no alloca.
    const float* Whb = Wh + (size_t)(tk * 16) * U + tc;
    f32x16 w0, w1, w2, w3, w4, w5, w6, w7, w8, w9, w10, w11, w12, w13, w14, w15;
#define LOADW(i)                                                        \
    {                                                                   \
        _Pragma("unroll")                                               \
        for (int j = 0; j < 16; ++j) w##i[j] = Whb[(size_t)(i) * U + 32 * j]; \
    }
    LOADW(0)  LOADW(1)  LOADW(2)  LOADW(3)
    LOADW(4)  LOADW(5)  LOADW(6)  LOADW(7)
    LOADW(8)  LOADW(9)  LOADW(10) LOADW(11)
    LOADW(12) LOADW(13) LOADW(14) LOADW(15)
#undef LOADW

    // h_0 = 0
    for (int c = tid; c < U; c += 1024) h_lds[c] = 0.f;
    __syncthreads();

    float* outb = out + (size_t)b * U;   // row (t*B + b) = outb + t*B*U

    for (int t = 0; t < T; ++t) {
        float* prow = outb + (size_t)t * B * U;

        // prefetch P value for this step (consumed after the mid barrier,
        // so its HBM latency hides under the FMA phase)
        float pv = 0.f;
        if (tid < U) pv = prow[tid];

        // h fragment: 4x float4 broadcast reads (2 distinct addrs per wave)
        float4 ha = *reinterpret_cast<const float4*>(&h_lds[tk * 16 + 0]);
        float4 hb = *reinterpret_cast<const float4*>(&h_lds[tk * 16 + 4]);
        float4 hc = *reinterpret_cast<const float4*>(&h_lds[tk * 16 + 8]);
        float4 hd = *reinterpret_cast<const float4*>(&h_lds[tk * 16 + 12]);

        f32x16 acc = (f32x16)0.f;
        acc += ha.x * w0;  acc += ha.y * w1;  acc += ha.z * w2;  acc += ha.w * w3;
        acc += hb.x * w4;  acc += hb.y * w5;  acc += hb.z * w6;  acc += hb.w * w7;
        acc += hc.x * w8;  acc += hc.y * w9;  acc += hc.z * w10; acc += hc.w * w11;
        acc += hd.x * w12; acc += hd.y * w13; acc += hd.z * w14; acc += hd.w * w15;

        // partials: bank = (tc + tk) & 31 -> permutation per 32-lane half
#pragma unroll
        for (int j = 0; j < 16; ++j)
            part[tc + 32 * j][tk] = acc[j];

        __syncthreads();   // partials visible

        if (tid < U) {
            float s = pv;
#pragma unroll
            for (int i = 0; i < 32; ++i) s += part[tid][i];
            float h = tanhf(s);
            prow[tid]  = h;     // overwrite P with h (final output)
            h_lds[tid] = h;     // state for next step
        }

        __syncthreads();   // h_lds visible for next step
    }
}

// ---------------------------------------------------------------------------
extern "C" void kernel_launch(void* const* d_in, const int* in_sizes, int n_in,
                              void* d_out, int out_size, void* d_ws, size_t ws_size,
                              hipStream_t stream)
{
    const float* x    = (const float*)d_in[0];  // [B, T, D]
    const float* Wx   = (const float*)d_in[1];  // [D, U]
    const float* Wh   = (const float*)d_in[2];  // [U, U]
    const float* bias = (const float*)d_in[3];  // [U]
    float* out = (float*)d_out;                 // [T, B, U]

    pgemm_kernel<<<dim3((T * B) / 128, U / 128), 256, 0, stream>>>(x, Wx, bias, out);
    rnn_kernel<<<B, 1024, 0, stream>>>(Wh, out);
}

// Round 3
// 1343.733 us; speedup vs baseline: 28.6979x; 28.6979x over previous
//
#include <hip/hip_runtime.h>
#include <stddef.h>
#include <stdint.h>

// Elman RNN: out[t,b,u] = h_t = tanh(x_t @ Wx + h_{t-1} @ Wh + bias)
// B=128, T=512, D=128, U=512. Output [T, B, U] float32.
//
// pgemm: P = x@Wx + bias written into d_out (f32, full precision).
// rnn:   one WG (512 thr) per batch row. Wh converted to f16 once per WG:
//        192 VGPRs/thread (12 named u32x16 SSA vectors, materialized via LDS
//        staging) + 128 KB LDS remainder. v_dot2_f32_f16 (f32 accumulate).
//        Pool math: WG=512 -> 2 waves/SIMD -> 256 VGPR cap; we use ~250.

constexpr int B = 128;
constexpr int T = 512;
constexpr int D = 128;
constexpr int U = 512;

typedef _Float16 f16;
typedef _Float16 f16x2 __attribute__((ext_vector_type(2)));
typedef unsigned int u32;
typedef u32 u32x16 __attribute__((ext_vector_type(16)));

static __device__ __forceinline__ f16x2 u2h(u32 x) {
    union { u32 u; f16x2 h; } c; c.u = x; return c.h;
}

#if __has_builtin(__builtin_amdgcn_fdot2)
static __device__ __forceinline__ float fdot2(u32 a, u32 b, float c) {
    return __builtin_amdgcn_fdot2(u2h(a), u2h(b), c, false);
}
#else
static __device__ __forceinline__ float fdot2(u32 a, u32 b, float c) {
    f16x2 ha = u2h(a), hb = u2h(b);
    return c + (float)ha.x * (float)hb.x + (float)ha.y * (float)hb.y;
}
#endif

// ---------------------------------------------------------------------------
// Kernel 1: P = x @ Wx + bias   (M=T*B rows in (t,b) order, K=D, N=U) — f32
// ---------------------------------------------------------------------------
__global__ __launch_bounds__(256) void pgemm_kernel(
    const float* __restrict__ x,     // [B, T, D]
    const float* __restrict__ Wx,    // [D, U]
    const float* __restrict__ bias,  // [U]
    float* __restrict__ P)           // [T*B, U]  (== d_out)
{
    __shared__ float xs[128][65];
    __shared__ float ws[64][128];

    const int rb  = blockIdx.x;
    const int cb  = blockIdx.y;
    const int tid = threadIdx.x;
    const int tr  = tid >> 4;
    const int tcc = tid & 15;

    float acc[8][8];
#pragma unroll
    for (int i = 0; i < 8; ++i)
#pragma unroll
        for (int j = 0; j < 8; ++j) acc[i][j] = 0.f;

    for (int kb = 0; kb < 2; ++kb) {
#pragma unroll
        for (int l = 0; l < 32; ++l) {
            int idx = tid + l * 256;
            int r   = idx >> 6;
            int k   = idx & 63;
            int m   = rb * 128 + r;
            int b_  = m & 127;
            int t_  = m >> 7;
            xs[r][k] = x[((size_t)b_ * T + t_) * D + kb * 64 + k];
        }
#pragma unroll
        for (int l = 0; l < 32; ++l) {
            int idx = tid + l * 256;
            int k   = idx >> 7;
            int c   = idx & 127;
            ws[k][c] = Wx[(size_t)(kb * 64 + k) * U + cb * 128 + c];
        }
        __syncthreads();

#pragma unroll 4
        for (int k = 0; k < 64; ++k) {
            float xv[8], wv[8];
#pragma unroll
            for (int i = 0; i < 8; ++i) xv[i] = xs[tr + 16 * i][k];
#pragma unroll
            for (int j = 0; j < 8; ++j) wv[j] = ws[k][tcc + 16 * j];
#pragma unroll
            for (int i = 0; i < 8; ++i)
#pragma unroll
                for (int j = 0; j < 8; ++j)
                    acc[i][j] += xv[i] * wv[j];
        }
        __syncthreads();
    }

#pragma unroll
    for (int j = 0; j < 8; ++j) {
        int c    = cb * 128 + tcc + 16 * j;
        float bv = bias[c];
#pragma unroll
        for (int i = 0; i < 8; ++i) {
            int m = rb * 128 + tr + 16 * i;
            P[(size_t)m * U + c] = acc[i][j] + bv;
        }
    }
}

// ---------------------------------------------------------------------------
// Kernel 2: recurrence, one WG (512 thr) per batch row.
//   tk = tid&15, tc = tid>>4.  Thread owns k-pairs p = tk + 16q (q=0..15),
//   cols c = tc + 32j (j=0..15).  q<12 -> registers W0..W11; q>=12 -> LDS.
//   Reduction over tk: 1 shfl_xor level, then part[c][tk&7] (stride 9).
// ---------------------------------------------------------------------------
__global__ __launch_bounds__(512, 2) void rnn_kernel(
    const float* __restrict__ Wh,    // [U, U] f32
    float* __restrict__ out)         // [T*B, U]; P on entry, h on exit
{
    // LDS plan (147 KB):
    //   [0, 131072)          WhL: f16 remainder of Wh (q=12..15), lane-major
    //   [131072, 149504)     part[512*9] f32   (loop)   | tile 16 KB (init)
    //   [149504, 150528)     h16[512] f16
    __shared__ __align__(16) char smem[150528];
    f16*  WhL   = (f16*)smem;
    u32*  wl32  = (u32*)smem;
    const uint4* WhL4 = (const uint4*)smem;
    float* part = (float*)(smem + 131072);
    f16*  h16   = (f16*)(smem + 131072 + 18432);
    f16*  tile  = (f16*)(smem + 131072);          // init-time alias

    const int tid = threadIdx.x;
    const int tk  = tid & 15;
    const int tc  = tid >> 4;
    const int b   = blockIdx.x;

    const float4* Wh4 = (const float4*)Wh;

    // ---- init: convert Wh f32 -> f16, distribute to regs + LDS ----
    u32x16 W0, W1, W2, W3, W4, W5, W6, W7, W8, W9, W10, W11;

    auto stage = [&](int kb, int co) {
        int r   = tid >> 4;           // 0..31 (row within 32-row band)
        int fcb = tid & 15;           // float4-col group
#pragma unroll
        for (int i = 0; i < 4; ++i) {
            float4 v = Wh4[(size_t)(kb * 32 + r) * 128 + co * 64 + fcb + 16 * i];
            int c2 = (fcb + 16 * i) * 4;
            tile[(c2 + 0) * 32 + r] = (f16)v.x;
            tile[(c2 + 1) * 32 + r] = (f16)v.y;
            tile[(c2 + 2) * 32 + r] = (f16)v.z;
            tile[(c2 + 3) * 32 + r] = (f16)v.w;
        }
    };

#define EXTRACT_REG(q, co)                                              \
    {                                                                   \
        const u32* t32 = (const u32*)tile;                              \
        _Pragma("unroll")                                               \
        for (int jj = 0; jj < 8; ++jj) {                                \
            W##q[8 * (co) + jj] = t32[(tc + 32 * jj) * 16 + tk];        \
        }                                                               \
    }

#define DO_REG(q)                                                       \
    stage(q, 0); __syncthreads(); EXTRACT_REG(q, 0); __syncthreads();   \
    stage(q, 1); __syncthreads(); EXTRACT_REG(q, 1); __syncthreads();

    DO_REG(0)  DO_REG(1)  DO_REG(2)  DO_REG(3)
    DO_REG(4)  DO_REG(5)  DO_REG(6)  DO_REG(7)
    DO_REG(8)  DO_REG(9)  DO_REG(10) DO_REG(11)
#undef DO_REG
#undef EXTRACT_REG

    auto extract_lds = [&](int q, int co) {
        const u32* t32 = (const u32*)tile;
#pragma unroll
        for (int jj = 0; jj < 8; ++jj) {
            int j = 8 * co + jj;
            wl32[((q - 12) * 4 + (j >> 2)) * 2048 + tid * 4 + (j & 3)] =
                t32[(tc + 32 * jj) * 16 + tk];
        }
    };
    for (int q = 12; q < 16; ++q) {
        stage(q, 0); __syncthreads(); extract_lds(q, 0); __syncthreads();
        stage(q, 1); __syncthreads(); extract_lds(q, 1); __syncthreads();
    }

    // h_0 = 0
    if (tid < 256) ((u32*)h16)[tid] = 0u;
    __syncthreads();

    const u32* h32 = (const u32*)h16;
    float* outb = out + (size_t)b * U;

    // ---- recurrence ----
    for (int t = 0; t < T; ++t) {
        float* prow = outb + (size_t)t * (B * U);

        // prefetch P (consumed after barrier -> latency hidden under dot2s)
        float pv = prow[tid];

        // h pairs: pair p = tk + 16q at uint index p (conflict-free)
        u32 hp[16];
#pragma unroll
        for (int q = 0; q < 16; ++q) hp[q] = h32[tk + 16 * q];

        float acc[16];
#pragma unroll
        for (int j = 0; j < 16; ++j) acc[j] = 0.f;

#define DOQ(q)                                                          \
        {                                                               \
            u32 hq = hp[q];                                             \
            _Pragma("unroll")                                           \
            for (int j = 0; j < 16; ++j)                                \
                acc[j] = fdot2(hq, W##q[j], acc[j]);                    \
        }
        DOQ(0)  DOQ(1)  DOQ(2)  DOQ(3)
        DOQ(4)  DOQ(5)  DOQ(6)  DOQ(7)
        DOQ(8)  DOQ(9)  DOQ(10) DOQ(11)
#undef DOQ

        // LDS-resident q = 12..15 (uint4 reads, lane-major, conflict-free)
#pragma unroll
        for (int qq = 0; qq < 4; ++qq) {
            u32 hq = hp[12 + qq];
            uint4 wa = WhL4[(qq * 4 + 0) * 512 + tid];
            uint4 wb = WhL4[(qq * 4 + 1) * 512 + tid];
            uint4 wc = WhL4[(qq * 4 + 2) * 512 + tid];
            uint4 wd = WhL4[(qq * 4 + 3) * 512 + tid];
            acc[0]  = fdot2(hq, wa.x, acc[0]);
            acc[1]  = fdot2(hq, wa.y, acc[1]);
            acc[2]  = fdot2(hq, wa.z, acc[2]);
            acc[3]  = fdot2(hq, wa.w, acc[3]);
            acc[4]  = fdot2(hq, wb.x, acc[4]);
            acc[5]  = fdot2(hq, wb.y, acc[5]);
            acc[6]  = fdot2(hq, wb.z, acc[6]);
            acc[7]  = fdot2(hq, wb.w, acc[7]);
            acc[8]  = fdot2(hq, wc.x, acc[8]);
            acc[9]  = fdot2(hq, wc.y, acc[9]);
            acc[10] = fdot2(hq, wc.z, acc[10]);
            acc[11] = fdot2(hq, wc.w, acc[11]);
            acc[12] = fdot2(hq, wd.x, acc[12]);
            acc[13] = fdot2(hq, wd.y, acc[13]);
            acc[14] = fdot2(hq, wd.z, acc[14]);
            acc[15] = fdot2(hq, wd.w, acc[15]);
        }

        // reduce over tk: 1 shfl level (tk bit 3), then LDS partials
#pragma unroll
        for (int j = 0; j < 16; ++j) acc[j] += __shfl_xor(acc[j], 8);

        if (!(tk & 8)) {
#pragma unroll
            for (int j = 0; j < 16; ++j)
                part[(tc + 32 * j) * 9 + tk] = acc[j];
        }
        __syncthreads();

        // per-col final: c = tid (512 threads = 512 cols)
        float s = pv;
#pragma unroll
        for (int i = 0; i < 8; ++i) s += part[tid * 9 + i];
        float hv = tanhf(s);
        prow[tid] = hv;            // final output (f32)
        h16[tid]  = (f16)hv;       // state for next step

        __syncthreads();
    }
}

// ---------------------------------------------------------------------------
extern "C" void kernel_launch(void* const* d_in, const int* in_sizes, int n_in,
                              void* d_out, int out_size, void* d_ws, size_t ws_size,
                              hipStream_t stream)
{
    (void)d_ws; (void)ws_size; (void)in_sizes; (void)n_in; (void)out_size;
    const float* x    = (const float*)d_in[0];  // [B, T, D]
    const float* Wx   = (const float*)d_in[1];  // [D, U]
    const float* Wh   = (const float*)d_in[2];  // [U, U]
    const float* bias = (const float*)d_in[3];  // [U]
    float* out = (float*)d_out;                 // [T, B, U]

    pgemm_kernel<<<dim3((T * B) / 128, U / 128), 256, 0, stream>>>(x, Wx, bias, out);
    rnn_kernel<<<B, 512, 0, stream>>>(Wh, out);
}

// Round 5
// 1033.543 us; speedup vs baseline: 37.3108x; 1.3001x over previous
//
#include <hip/hip_runtime.h>
#include <stddef.h>
#include <stdint.h>

// Elman RNN: out[t,b,u] = h_t = tanh(x_t @ Wx + h_{t-1} @ Wh + bias)
// B=128, T=512, D=128, U=512. Output [T, B, U] float32.
//
// pgemm (f16 dot2): P = x@Wx + bias -> d_out (f32 accum/store).
// rnn: one WG (512 thr) per batch row.
//   tk = tid>>5 owns 16 contiguous k-pairs (pairs 16tk..16tk+15).
//   tc = tid&31 owns cols c = tc + 32j, j=0..15.
//   W: pairs pl=0..11 in 12 named u32x16 regs (192 VGPR), pl=12..15 in LDS
//   (128 KB, lane-major uint4).  Register budget ~232 < 256 cap (512thr,2w/EU).
//   Reduce: packed-f16 partials (cvt_pkrtz) -> part[16][264] u32 (16.9 KB),
//   reader thread c<256 handles cols c and c+256. Fast tanh via v_exp+v_rcp.

constexpr int B = 128;
constexpr int T = 512;
constexpr int D = 128;
constexpr int U = 512;

typedef _Float16 f16;
typedef _Float16 f16x2 __attribute__((ext_vector_type(2)));
typedef __fp16   fp16x2 __attribute__((ext_vector_type(2)));
typedef unsigned int u32;
typedef u32 u32x16 __attribute__((ext_vector_type(16)));

union U32H2 { u32 u; f16x2 h; fp16x2 p; };

static __device__ __forceinline__ u32 pk(float a, float b) {
    U32H2 c; c.p = __builtin_amdgcn_cvt_pkrtz(a, b); return c.u;
}

#if __has_builtin(__builtin_amdgcn_fdot2)
static __device__ __forceinline__ float fdot2(u32 a, u32 b, float c) {
    U32H2 x, y; x.u = a; y.u = b;
    return __builtin_amdgcn_fdot2(x.h, y.h, c, false);
}
#else
static __device__ __forceinline__ float fdot2(u32 a, u32 b, float c) {
    U32H2 x, y; x.u = a; y.u = b;
    return c + (float)x.h.x * (float)y.h.x + (float)x.h.y * (float)y.h.y;
}
#endif

static __device__ __forceinline__ float fast_tanh(float x) {
    float e = __expf(2.0f * x);                       // v_mul + v_exp
    return 1.0f - 2.0f * __builtin_amdgcn_rcpf(e + 1.0f);
}

// ---------------------------------------------------------------------------
// Kernel 1: P = x @ Wx + bias  (M=T*B, K=D=128 one-shot, N=U) — f16 dot2
// 256 thr, 128x128 tile, LDS 67.6 KB -> 2 WG/CU.
// ---------------------------------------------------------------------------
__global__ __launch_bounds__(256) void pgemm_kernel(
    const float* __restrict__ x,     // [B, T, D]
    const float* __restrict__ Wx,    // [D, U]
    const float* __restrict__ bias,  // [U]
    float* __restrict__ P)           // [T*B, U]  (== d_out)
{
    __shared__ u32 xs[128][66];      // [row][k-pair]   (+2 pad)
    __shared__ u32 ws[64][132];      // [k-pair][col]   (+4 pad)

    const int rb  = blockIdx.x;      // 512 row blocks of 128
    const int cb  = blockIdx.y;      // 4 col blocks of 128
    const int tid = threadIdx.x;
    const int tr  = tid >> 4;        // 0..15
    const int tcc = tid & 15;        // 0..15

    // stage x: 128 rows x 32 float4 = 4096 float4 -> f16 pairs
    const float4* x4 = (const float4*)x;
#pragma unroll
    for (int l = 0; l < 16; ++l) {
        int idx = tid + l * 256;     // 0..4095
        int r   = idx >> 5;          // 0..127
        int q   = idx & 31;          // float4 within row
        int m   = rb * 128 + r;
        int b_  = m & 127;
        int t_  = m >> 7;
        float4 v = x4[((size_t)b_ * T + t_) * 32 + q];
        xs[r][2 * q]     = pk(v.x, v.y);
        xs[r][2 * q + 1] = pk(v.z, v.w);
    }
    // stage Wx: pack along K: w[kp][c] = {Wx[2kp][c], Wx[2kp+1][c]}
    const float4* W4 = (const float4*)Wx;
#pragma unroll
    for (int l = 0; l < 8; ++l) {
        int idx = tid + l * 256;     // 0..2047
        int kp  = idx >> 5;          // 0..63
        int q   = idx & 31;          // col-quad within 128-col block
        float4 a = W4[(size_t)(2 * kp)     * 128 + cb * 32 + q];
        float4 c = W4[(size_t)(2 * kp + 1) * 128 + cb * 32 + q];
        uint4 w;
        w.x = pk(a.x, c.x); w.y = pk(a.y, c.y);
        w.z = pk(a.z, c.z); w.w = pk(a.w, c.w);
        *(uint4*)&ws[kp][4 * q] = w;
    }
    __syncthreads();

    float acc[8][8];
#pragma unroll
    for (int i = 0; i < 8; ++i)
#pragma unroll
        for (int j = 0; j < 8; ++j) acc[i][j] = 0.f;

#pragma unroll 2
    for (int kp = 0; kp < 64; ++kp) {
        u32 xv[8], wv[8];
#pragma unroll
        for (int i = 0; i < 8; ++i) xv[i] = xs[tr + 16 * i][kp];
#pragma unroll
        for (int j = 0; j < 8; ++j) wv[j] = ws[kp][tcc + 16 * j];
#pragma unroll
        for (int i = 0; i < 8; ++i)
#pragma unroll
            for (int j = 0; j < 8; ++j)
                acc[i][j] = fdot2(xv[i], wv[j], acc[i][j]);
    }

#pragma unroll
    for (int j = 0; j < 8; ++j) {
        int c    = cb * 128 + tcc + 16 * j;
        float bv = bias[c];
#pragma unroll
        for (int i = 0; i < 8; ++i) {
            int m = rb * 128 + tr + 16 * i;
            P[(size_t)m * U + c] = acc[i][j] + bv;
        }
    }
}

// ---------------------------------------------------------------------------
// Kernel 2: recurrence, one WG (512 thr) per batch row.
// ---------------------------------------------------------------------------
__global__ __launch_bounds__(512, 2) void rnn_kernel(
    const float* __restrict__ Wh,    // [U, U] f32
    float* __restrict__ out)         // [T*B, U]; P on entry, h on exit
{
    __shared__ __align__(16) u32 WhL[32768];      // 128 KB: pairs 12..15
    __shared__ __align__(16) u32 part[16 * 264];  // 16.9 KB packed partials
    __shared__ __align__(16) u32 hbuf[320];       // h pairs, padded p+4*(p>>4)

    const int tid = threadIdx.x;
    const int tk  = tid >> 5;        // 0..15 pair-block
    const int tc  = tid & 31;        // 0..31 col base
    const int b   = blockIdx.x;

    // ---- init: W registers (pairs 0..11 of this tk-block) ----
    u32x16 W0, W1, W2, W3, W4, W5, W6, W7, W8, W9, W10, W11;
#define LOADW(q)                                                          \
    {                                                                     \
        const float* r0 = Wh + (size_t)((tk * 16 + (q)) * 2) * U + tc;    \
        _Pragma("unroll")                                                 \
        for (int j = 0; j < 16; ++j)                                      \
            W##q[j] = pk(r0[32 * j], r0[U + 32 * j]);                     \
    }
    LOADW(0)  LOADW(1)  LOADW(2)  LOADW(3)
    LOADW(4)  LOADW(5)  LOADW(6)  LOADW(7)
    LOADW(8)  LOADW(9)  LOADW(10) LOADW(11)
#undef LOADW

    // ---- init: LDS pairs 12..15, lane-major uint4 ----
#pragma unroll
    for (int pl2 = 0; pl2 < 4; ++pl2) {
        const float* r0 = Wh + (size_t)((tk * 16 + 12 + pl2) * 2) * U + tc;
#pragma unroll
        for (int jc = 0; jc < 4; ++jc) {
            uint4 w;
            w.x = pk(r0[32 * (4 * jc + 0)], r0[U + 32 * (4 * jc + 0)]);
            w.y = pk(r0[32 * (4 * jc + 1)], r0[U + 32 * (4 * jc + 1)]);
            w.z = pk(r0[32 * (4 * jc + 2)], r0[U + 32 * (4 * jc + 2)]);
            w.w = pk(r0[32 * (4 * jc + 3)], r0[U + 32 * (4 * jc + 3)]);
            *(uint4*)&WhL[((pl2 * 4 + jc) * 512 + tid) * 4] = w;
        }
    }

    // h_0 = 0
    if (tid < 320) hbuf[tid] = 0u;
    __syncthreads();

    float* outb = out + (size_t)b * U;
    f16* hb16 = (f16*)hbuf;
    // h-store f16 index for col c=tid (<256): p=c>>1, idx16 = 2*(p+4*(p>>4))+(c&1)
    const int p0    = tid >> 1;
    const int hidx  = 2 * (p0 + 4 * (p0 >> 4)) + (tid & 1);   // col tid
    // col tid+256 -> idx + 320

    // prefetch P for t = 0
    float pv0 = 0.f, pv1 = 0.f;
    if (tid < 256) { pv0 = outb[tid]; pv1 = outb[tid + 256]; }

    for (int t = 0; t < T; ++t) {
        // issue next-step prefetch early (consumed next iteration)
        int tn = (t + 1 < T) ? (t + 1) : t;
        const float* prown = outb + (size_t)tn * (B * U);
        float nv0 = 0.f, nv1 = 0.f;
        if (tid < 256) { nv0 = prown[tid]; nv1 = prown[tid + 256]; }

        float acc[16];
#pragma unroll
        for (int j = 0; j < 16; ++j) acc[j] = 0.f;

        const uint4* h4p = (const uint4*)&hbuf[20 * tk];

#define DOT16(hq, Wq)                                                     \
        {                                                                 \
            u32 hq_ = (hq);                                               \
            _Pragma("unroll")                                             \
            for (int j = 0; j < 16; ++j)                                  \
                acc[j] = fdot2(hq_, Wq[j], acc[j]);                       \
        }
        { uint4 hv = h4p[0];
          DOT16(hv.x, W0) DOT16(hv.y, W1) DOT16(hv.z, W2) DOT16(hv.w, W3) }
        { uint4 hv = h4p[1];
          DOT16(hv.x, W4) DOT16(hv.y, W5) DOT16(hv.z, W6) DOT16(hv.w, W7) }
        { uint4 hv = h4p[2];
          DOT16(hv.x, W8) DOT16(hv.y, W9) DOT16(hv.z, W10) DOT16(hv.w, W11) }
#undef DOT16

        // LDS-resident pairs 12..15
        {
            uint4 hv = h4p[3];
#pragma unroll
            for (int pl2 = 0; pl2 < 4; ++pl2) {
                u32 hq = (pl2 == 0) ? hv.x : (pl2 == 1) ? hv.y
                       : (pl2 == 2) ? hv.z : hv.w;
#pragma unroll
                for (int jc = 0; jc < 4; ++jc) {
                    uint4 w = *(const uint4*)&WhL[((pl2 * 4 + jc) * 512 + tid) * 4];
                    acc[4 * jc + 0] = fdot2(hq, w.x, acc[4 * jc + 0]);
                    acc[4 * jc + 1] = fdot2(hq, w.y, acc[4 * jc + 1]);
                    acc[4 * jc + 2] = fdot2(hq, w.z, acc[4 * jc + 2]);
                    acc[4 * jc + 3] = fdot2(hq, w.w, acc[4 * jc + 3]);
                }
            }
        }

        // packed partials: u32 {col c (lo f16), col c+256 (hi f16)}
#pragma unroll
        for (int j = 0; j < 8; ++j)
            part[tk * 264 + tc + 32 * j] = pk(acc[j], acc[j + 8]);

        __syncthreads();   // partials visible

        if (tid < 256) {
            float s0 = pv0, s1 = pv1;
#pragma unroll
            for (int i = 0; i < 16; ++i) {
                U32H2 w; w.u = part[i * 264 + tid];
                s0 += (float)w.h.x;
                s1 += (float)w.h.y;
            }
            float h0 = fast_tanh(s0);
            float h1 = fast_tanh(s1);
            float* prow = outb + (size_t)t * (B * U);
            prow[tid]        = h0;     // final output (f32)
            prow[tid + 256]  = h1;
            hb16[hidx]       = (f16)h0; // state for next step
            hb16[hidx + 320] = (f16)h1;
        }
        pv0 = nv0; pv1 = nv1;

        __syncthreads();   // h visible for next step
    }
}

// ---------------------------------------------------------------------------
extern "C" void kernel_launch(void* const* d_in, const int* in_sizes, int n_in,
                              void* d_out, int out_size, void* d_ws, size_t ws_size,
                              hipStream_t stream)
{
    (void)d_ws; (void)ws_size; (void)in_sizes; (void)n_in; (void)out_size;
    const float* x    = (const float*)d_in[0];  // [B, T, D]
    const float* Wx   = (const float*)d_in[1];  // [D, U]
    const float* Wh   = (const float*)d_in[2];  // [U, U]
    const float* bias = (const float*)d_in[3];  // [U]
    float* out = (float*)d_out;                 // [T, B, U]

    pgemm_kernel<<<dim3((T * B) / 128, U / 128), 256, 0, stream>>>(x, Wx, bias, out);
    rnn_kernel<<<B, 512, 0, stream>>>(Wh, out);
}

// Round 6
// 989.890 us; speedup vs baseline: 38.9561x; 1.0441x over previous
//
#include <hip/hip_runtime.h>
#include <stddef.h>
#include <stdint.h>

// Elman RNN: out[t,b,u] = h_t = tanh(x_t @ Wx + h_{t-1} @ Wh + bias)
// B=128, T=512, D=128, U=512. Output [T, B, U] float32.
//
// pgemm (f16 dot2): P = x@Wx + bias -> d_out (f32 accum/store). ~15 us.
// rnn: one WG (512 thr) per batch row.
//   tk = tid>>5 owns 16 contiguous k-pairs, tc = tid&31 owns 16 cols.
//   W pairs 0..11 in 12 named u32x16 regs (192 words), pairs 12..15 in LDS.
//   amdgpu_waves_per_eu(2,2): stop the allocator from chasing >2 waves/EU —
//   unlock the full 256-VGPR budget (round 3/5: it chose 128 + AGPR spills).
//   W-LDS uint4 reads hoisted before the reg-dot phase + 1-batch lookahead
//   so ds_read latency hides under the 192 reg dot2s.

constexpr int B = 128;
constexpr int T = 512;
constexpr int D = 128;
constexpr int U = 512;

typedef _Float16 f16;
typedef _Float16 f16x2 __attribute__((ext_vector_type(2)));
typedef __fp16   fp16x2 __attribute__((ext_vector_type(2)));
typedef unsigned int u32;
typedef u32 u32x16 __attribute__((ext_vector_type(16)));

union U32H2 { u32 u; f16x2 h; fp16x2 p; };

static __device__ __forceinline__ u32 pk(float a, float b) {
    U32H2 c; c.p = __builtin_amdgcn_cvt_pkrtz(a, b); return c.u;
}

#if __has_builtin(__builtin_amdgcn_fdot2)
static __device__ __forceinline__ float fdot2(u32 a, u32 b, float c) {
    U32H2 x, y; x.u = a; y.u = b;
    return __builtin_amdgcn_fdot2(x.h, y.h, c, false);
}
#else
static __device__ __forceinline__ float fdot2(u32 a, u32 b, float c) {
    U32H2 x, y; x.u = a; y.u = b;
    return c + (float)x.h.x * (float)y.h.x + (float)x.h.y * (float)y.h.y;
}
#endif

static __device__ __forceinline__ float fast_tanh(float x) {
    float e = __expf(2.0f * x);
    return 1.0f - 2.0f * __builtin_amdgcn_rcpf(e + 1.0f);
}

// ---------------------------------------------------------------------------
// Kernel 1: P = x @ Wx + bias  (M=T*B, K=D=128 one-shot, N=U) — f16 dot2
// ---------------------------------------------------------------------------
__global__ __launch_bounds__(256) void pgemm_kernel(
    const float* __restrict__ x,     // [B, T, D]
    const float* __restrict__ Wx,    // [D, U]
    const float* __restrict__ bias,  // [U]
    float* __restrict__ P)           // [T*B, U]  (== d_out)
{
    __shared__ u32 xs[128][66];      // [row][k-pair]   (+2 pad)
    __shared__ u32 ws[64][132];      // [k-pair][col]   (+4 pad)

    const int rb  = blockIdx.x;
    const int cb  = blockIdx.y;
    const int tid = threadIdx.x;
    const int tr  = tid >> 4;
    const int tcc = tid & 15;

    const float4* x4 = (const float4*)x;
#pragma unroll
    for (int l = 0; l < 16; ++l) {
        int idx = tid + l * 256;
        int r   = idx >> 5;
        int q   = idx & 31;
        int m   = rb * 128 + r;
        int b_  = m & 127;
        int t_  = m >> 7;
        float4 v = x4[((size_t)b_ * T + t_) * 32 + q];
        xs[r][2 * q]     = pk(v.x, v.y);
        xs[r][2 * q + 1] = pk(v.z, v.w);
    }
    const float4* W4 = (const float4*)Wx;
#pragma unroll
    for (int l = 0; l < 8; ++l) {
        int idx = tid + l * 256;
        int kp  = idx >> 5;
        int q   = idx & 31;
        float4 a = W4[(size_t)(2 * kp)     * 128 + cb * 32 + q];
        float4 c = W4[(size_t)(2 * kp + 1) * 128 + cb * 32 + q];
        uint4 w;
        w.x = pk(a.x, c.x); w.y = pk(a.y, c.y);
        w.z = pk(a.z, c.z); w.w = pk(a.w, c.w);
        *(uint4*)&ws[kp][4 * q] = w;
    }
    __syncthreads();

    float acc[8][8];
#pragma unroll
    for (int i = 0; i < 8; ++i)
#pragma unroll
        for (int j = 0; j < 8; ++j) acc[i][j] = 0.f;

#pragma unroll 2
    for (int kp = 0; kp < 64; ++kp) {
        u32 xv[8], wv[8];
#pragma unroll
        for (int i = 0; i < 8; ++i) xv[i] = xs[tr + 16 * i][kp];
#pragma unroll
        for (int j = 0; j < 8; ++j) wv[j] = ws[kp][tcc + 16 * j];
#pragma unroll
        for (int i = 0; i < 8; ++i)
#pragma unroll
            for (int j = 0; j < 8; ++j)
                acc[i][j] = fdot2(xv[i], wv[j], acc[i][j]);
    }

#pragma unroll
    for (int j = 0; j < 8; ++j) {
        int c    = cb * 128 + tcc + 16 * j;
        float bv = bias[c];
#pragma unroll
        for (int i = 0; i < 8; ++i) {
            int m = rb * 128 + tr + 16 * i;
            P[(size_t)m * U + c] = acc[i][j] + bv;
        }
    }
}

// ---------------------------------------------------------------------------
// Kernel 2: recurrence, one WG (512 thr) per batch row.
// ---------------------------------------------------------------------------
__global__ __launch_bounds__(512)
__attribute__((amdgpu_waves_per_eu(2, 2)))
void rnn_kernel(
    const float* __restrict__ Wh,    // [U, U] f32
    float* __restrict__ out)         // [T*B, U]; P on entry, h on exit
{
    __shared__ __align__(16) u32 WhL[32768];      // 128 KB: pairs 12..15
    __shared__ __align__(16) u32 part[16 * 264];  // 16.9 KB packed partials
    __shared__ __align__(16) u32 hbuf[320];       // h pairs, padded p+4*(p>>4)

    const int tid = threadIdx.x;
    const int tk  = tid >> 5;        // 0..15 pair-block
    const int tc  = tid & 31;        // 0..31 col base
    const int b   = blockIdx.x;

    // ---- init: W registers (pairs 0..11 of this tk-block) ----
    u32x16 W0, W1, W2, W3, W4, W5, W6, W7, W8, W9, W10, W11;
#define LOADW(q)                                                          \
    {                                                                     \
        const float* r0 = Wh + (size_t)((tk * 16 + (q)) * 2) * U + tc;    \
        _Pragma("unroll")                                                 \
        for (int j = 0; j < 16; ++j)                                      \
            W##q[j] = pk(r0[32 * j], r0[U + 32 * j]);                     \
    }
    LOADW(0)  LOADW(1)  LOADW(2)  LOADW(3)
    LOADW(4)  LOADW(5)  LOADW(6)  LOADW(7)
    LOADW(8)  LOADW(9)  LOADW(10) LOADW(11)
#undef LOADW

    // ---- init: LDS pairs 12..15, lane-major uint4 ----
#pragma unroll
    for (int pl2 = 0; pl2 < 4; ++pl2) {
        const float* r0 = Wh + (size_t)((tk * 16 + 12 + pl2) * 2) * U + tc;
#pragma unroll
        for (int jc = 0; jc < 4; ++jc) {
            uint4 w;
            w.x = pk(r0[32 * (4 * jc + 0)], r0[U + 32 * (4 * jc + 0)]);
            w.y = pk(r0[32 * (4 * jc + 1)], r0[U + 32 * (4 * jc + 1)]);
            w.z = pk(r0[32 * (4 * jc + 2)], r0[U + 32 * (4 * jc + 2)]);
            w.w = pk(r0[32 * (4 * jc + 3)], r0[U + 32 * (4 * jc + 3)]);
            *(uint4*)&WhL[((pl2 * 4 + jc) * 512 + tid) * 4] = w;
        }
    }

    // h_0 = 0
    if (tid < 320) hbuf[tid] = 0u;
    __syncthreads();

    float* outb = out + (size_t)b * U;
    f16* hb16 = (f16*)hbuf;
    const int p0    = tid >> 1;
    const int hidx  = 2 * (p0 + 4 * (p0 >> 4)) + (tid & 1);   // col tid

    const uint4* WL4 = (const uint4*)WhL;

    // prefetch P for t = 0
    float pv0 = 0.f, pv1 = 0.f;
    if (tid < 256) { pv0 = outb[tid]; pv1 = outb[tid + 256]; }

    for (int t = 0; t < T; ++t) {
        // next-step P prefetch (in flight across the whole step)
        int tn = (t + 1 < T) ? (t + 1) : t;
        const float* prown = outb + (size_t)tn * (B * U);
        float nv0 = 0.f, nv1 = 0.f;
        if (tid < 256) { nv0 = prown[tid]; nv1 = prown[tid + 256]; }

        // h fragments (broadcast reads, 2 distinct addrs per wave)
        const uint4* h4p = (const uint4*)&hbuf[20 * tk];
        uint4 hv0 = h4p[0];
        uint4 hv1 = h4p[1];
        uint4 hv2 = h4p[2];
        uint4 hv3 = h4p[3];

        // issue W-LDS batch 0 EARLY — independent of h, hides under reg dots
        uint4 wa = WL4[0 * 512 + tid];
        uint4 wb = WL4[1 * 512 + tid];
        uint4 wc = WL4[2 * 512 + tid];
        uint4 wd = WL4[3 * 512 + tid];

        float acc[16];
#pragma unroll
        for (int j = 0; j < 16; ++j) acc[j] = 0.f;

#define DOT16(hq, Wq)                                                     \
        {                                                                 \
            u32 hq_ = (hq);                                               \
            _Pragma("unroll")                                             \
            for (int j = 0; j < 16; ++j)                                  \
                acc[j] = fdot2(hq_, Wq[j], acc[j]);                       \
        }
        DOT16(hv0.x, W0) DOT16(hv0.y, W1) DOT16(hv0.z, W2) DOT16(hv0.w, W3)
        DOT16(hv1.x, W4) DOT16(hv1.y, W5) DOT16(hv1.z, W6) DOT16(hv1.w, W7)

        // issue W-LDS batch 1 midway
        uint4 we = WL4[4 * 512 + tid];
        uint4 wf = WL4[5 * 512 + tid];
        uint4 wg = WL4[6 * 512 + tid];
        uint4 wh = WL4[7 * 512 + tid];

        DOT16(hv2.x, W8) DOT16(hv2.y, W9) DOT16(hv2.z, W10) DOT16(hv2.w, W11)
#undef DOT16

#define CONSUME(hq, Aq, Bq, Cq, Dq)                                       \
        {                                                                 \
            u32 hq_ = (hq);                                               \
            acc[0]  = fdot2(hq_, Aq.x, acc[0]);                           \
            acc[1]  = fdot2(hq_, Aq.y, acc[1]);                           \
            acc[2]  = fdot2(hq_, Aq.z, acc[2]);                           \
            acc[3]  = fdot2(hq_, Aq.w, acc[3]);                           \
            acc[4]  = fdot2(hq_, Bq.x, acc[4]);                           \
            acc[5]  = fdot2(hq_, Bq.y, acc[5]);                           \
            acc[6]  = fdot2(hq_, Bq.z, acc[6]);                           \
            acc[7]  = fdot2(hq_, Bq.w, acc[7]);                           \
            acc[8]  = fdot2(hq_, Cq.x, acc[8]);                           \
            acc[9]  = fdot2(hq_, Cq.y, acc[9]);                           \
            acc[10] = fdot2(hq_, Cq.z, acc[10]);                          \
            acc[11] = fdot2(hq_, Cq.w, acc[11]);                          \
            acc[12] = fdot2(hq_, Dq.x, acc[12]);                          \
            acc[13] = fdot2(hq_, Dq.y, acc[13]);                          \
            acc[14] = fdot2(hq_, Dq.z, acc[14]);                          \
            acc[15] = fdot2(hq_, Dq.w, acc[15]);                          \
        }
        // consume batch 0, preload batch 2 into wa..wd slots afterwards
        CONSUME(hv3.x, wa, wb, wc, wd)
        wa = WL4[ 8 * 512 + tid];
        wb = WL4[ 9 * 512 + tid];
        wc = WL4[10 * 512 + tid];
        wd = WL4[11 * 512 + tid];
        CONSUME(hv3.y, we, wf, wg, wh)
        we = WL4[12 * 512 + tid];
        wf = WL4[13 * 512 + tid];
        wg = WL4[14 * 512 + tid];
        wh = WL4[15 * 512 + tid];
        CONSUME(hv3.z, wa, wb, wc, wd)
        CONSUME(hv3.w, we, wf, wg, wh)
#undef CONSUME

        // packed partials: u32 {col c (lo f16), col c+256 (hi f16)}
#pragma unroll
        for (int j = 0; j < 8; ++j)
            part[tk * 264 + tc + 32 * j] = pk(acc[j], acc[j + 8]);

        __syncthreads();   // partials visible

        if (tid < 256) {
            float s0 = pv0, s1 = pv1;
#pragma unroll
            for (int i = 0; i < 16; ++i) {
                U32H2 w; w.u = part[i * 264 + tid];
                s0 += (float)w.h.x;
                s1 += (float)w.h.y;
            }
            float h0 = fast_tanh(s0);
            float h1 = fast_tanh(s1);
            float* prow = outb + (size_t)t * (B * U);
            prow[tid]        = h0;     // final output (f32)
            prow[tid + 256]  = h1;
            hb16[hidx]       = (f16)h0; // state for next step
            hb16[hidx + 320] = (f16)h1;
        }
        pv0 = nv0; pv1 = nv1;

        __syncthreads();   // h visible for next step
    }
}

// ---------------------------------------------------------------------------
extern "C" void kernel_launch(void* const* d_in, const int* in_sizes, int n_in,
                              void* d_out, int out_size, void* d_ws, size_t ws_size,
                              hipStream_t stream)
{
    (void)d_ws; (void)ws_size; (void)in_sizes; (void)n_in; (void)out_size;
    const float* x    = (const float*)d_in[0];  // [B, T, D]
    const float* Wx   = (const float*)d_in[1];  // [D, U]
    const float* Wh   = (const float*)d_in[2];  // [U, U]
    const float* bias = (const float*)d_in[3];  // [U]
    float* out = (float*)d_out;                 // [T, B, U]

    pgemm_kernel<<<dim3((T * B) / 128, U / 128), 256, 0, stream>>>(x, Wx, bias, out);
    rnn_kernel<<<B, 512, 0, stream>>>(Wh, out);
}